// Round 8
// baseline (714.754 us; speedup 1.0000x reference)
//
#include <hip/hip_runtime.h>
#include <stdint.h>

// ---------------- problem constants ----------------
#define NP   250000
#define NA   10000
#define NBLK 5
#define NL   20            // 5 blocks x (2 iW + 2 oW) layers
#define BLOB_W_BYTES 32768               // 128x128 bf16, row=out-feature, XOR-swizzled chunks
#define BLOB_BYTES   33280               // + 128 fp32 folded biases (512 B)

#define LOG2E 1.4426950408889634f
#define LN2   0.6931471805599453f

typedef __bf16 bf16x8 __attribute__((ext_vector_type(8)));
typedef float  f32x4  __attribute__((ext_vector_type(4)));
typedef unsigned short ushort_t;
typedef unsigned int   uint_t;
typedef int4  i4_ma __attribute__((may_alias));
typedef uint2 u2_ma __attribute__((may_alias));

// raw single-instruction transcendentals (v_exp_f32 / v_log_f32); args bounded
#if __has_builtin(__builtin_amdgcn_exp2f)
#define FEXP2(x) __builtin_amdgcn_exp2f(x)
#else
#define FEXP2(x) exp2f(x)
#endif
#if __has_builtin(__builtin_amdgcn_logf)
#define FLOG2(x) __builtin_amdgcn_logf(x)
#else
#define FLOG2(x) log2f(x)
#endif

// ---------------- static device scratch ----------------
__device__ uint8_t g_blob[NL * BLOB_BYTES];   // swizzled bf16 weights + folded f32 biases
__device__ float   g_outs[NBLK * NA * 2];     // per-block per-atom segment sums
__device__ float   g_nh[1];
__device__ float   g_Rf[NA * 3];
__device__ float   g_oWfF[NBLK * 128 * 2];    // ln2-prescaled head weights
__device__ float   g_oBfF[NBLK * 2];          // head biases (unmodified)
__device__ float   g_scF[190];
__device__ float   g_shF[190];

static __device__ __forceinline__ float bf2f(ushort_t u) {
    return __uint_as_float(((uint_t)u) << 16);
}
static __device__ __forceinline__ ushort_t f2bf(float f) {   // RNE (prep only)
    uint_t u = __float_as_uint(f);
    u += 0x7fffu + ((u >> 16) & 1u);
    return (ushort_t)(u >> 16);
}
static __device__ __forceinline__ bf16x8 as_bf16x8(i4_ma v) {
    union { i4_ma i; bf16x8 b; } u; u.i = v; return u.b;
}
static __device__ __forceinline__ i4_ma as_i4(bf16x8 v) {
    union { bf16x8 b; i4_ma i; } u; u.b = v; return u.i;
}
// pack 2 floats -> bf16x2 dword by truncation (1 VALU op). RELATIVE error --
// safe because stored u decays with the signal (round-5 lesson).
static __device__ __forceinline__ uint_t pkbf(float a, float b) {
    return __byte_perm(__float_as_uint(a), __float_as_uint(b), 0x7632);
}
// stored activation: u = y/ln2 = log2(0.5 + 2^(t-1)); -1 folded into bias.
static __device__ __forceinline__ float ssp_u(float accv) {
    return FLOG2(0.5f + FEXP2(accv));
}

// dtype auto-detection (validated round 4: inputs are f32; keep as insurance)
static __device__ __forceinline__ bool detect_is_f32(const ushort_t* probe) {
    __shared__ int flag;
    if (threadIdx.x == 0) flag = 0;
    __syncthreads();
    if (threadIdx.x < 256) {
        float v = fabsf(bf2f(probe[2 * threadIdx.x]));
        if (!(v <= 64.0f)) flag = 1;
    }
    __syncthreads();
    return flag != 0;
}
static __device__ __forceinline__ float in_elt(const void* p, int i, bool isf32) {
    return isf32 ? ((const float*)p)[i] : bf2f(((const ushort_t*)p)[i]);
}

// ---------------- zero accumulators ----------------
__global__ void zero_outs()
{
    const int t = blockIdx.x * 256 + threadIdx.x;
    if (t < NBLK * NA * 2) g_outs[t] = 0.0f;
    if (t == 0) g_nh[0] = 0.0f;
}

// ---------------- weight prep ----------------
// blob[L]: row m (out-feature) * 128 bf16; chunk c=k>>3 at 8*((k>>3)^(m&15))+(k&7).
// L==0: W prescaled by log2e (input is raw basis). L>=1: W unscaled (input is u).
// bias = b*log2e - 1 (implements the s->u shift inside the acc).
__global__ void prep_weights(const void* __restrict__ iW, const void* __restrict__ iB,
                             const void* __restrict__ oW, const void* __restrict__ oB)
{
    const bool isf32 = detect_is_f32((const ushort_t*)iW);
    const int L = blockIdx.x;           // 0..19
    const int b = L >> 2, li = L & 3;
    const void* srcW = (li < 2) ? iW : oW;
    const void* srcB = (li < 2) ? iB : oB;
    const int lyr = (li < 2) ? (b * 2 + li) : (b * 2 + li - 2);
    const int wofs = lyr * 16384;
    const int bofs = lyr * 128;
    uint8_t* blob = g_blob + (size_t)L * BLOB_BYTES;
    ushort_t* dw = (ushort_t*)blob;
    float*    db = (float*)(blob + BLOB_W_BYTES);
    for (int idx = threadIdx.x; idx < 16384; idx += blockDim.x) {
        int k = idx >> 7, n = idx & 127;               // src: W[k][n] (k=in, n=out)
        float w = in_elt(srcW, wofs + k * 128 + n, isf32);
        if (L == 0) w *= LOG2E;
        dw[n * 128 + 8 * ((k >> 3) ^ (n & 15)) + (k & 7)] = f2bf(w);
    }
    for (int m = threadIdx.x; m < 128; m += blockDim.x)
        db[m] = in_elt(srcB, bofs + m, isf32) * LOG2E - 1.0f;
}

// canonical f32 copies; head weights prescaled by ln2 (u -> y factor)
__global__ void prep_misc(const void* __restrict__ R, const void* __restrict__ oWf,
                          const void* __restrict__ oBf, const void* __restrict__ scales,
                          const void* __restrict__ shifts, const void* __restrict__ iW)
{
    const bool isf32 = detect_is_f32((const ushort_t*)iW);
    const int t = blockIdx.x * 256 + threadIdx.x;
    if (t < NA * 3)      g_Rf[t]   = in_elt(R, t, isf32);
    if (t < NBLK * 256)  g_oWfF[t] = LN2 * in_elt(oWf, t, isf32);
    if (t < NBLK * 2)    g_oBfF[t] = in_elt(oBf, t, isf32);
    if (t < 190)         g_scF[t]  = in_elt(scales, t, isf32);
    if (t < 190)         g_shF[t]  = in_elt(shifts, t, isf32);
}

// ---------------- fused per-pair MLP ----------------
// 128-thread wg = 2 independent waves; each wave owns 32 pairs and a private
// 8 KB in-place LDS act buffer (in-place is safe: all ds_reads of a layer
// precede all its ds_writes through the acc data-dependence, and LDS ops
// complete in issue order within a wave). x is carried across li2/li3 in
// 32 VGPRs (li2's B-frags == next block's li0 input), so li0 needs no LDS.
// 16 KB/wg -> 10 wg/CU; VGPR ~116 -> 4 waves/SIMD cap -> 16 waves/CU.
__global__ __launch_bounds__(128, 4)
void pairs_mlp_kernel(const int* __restrict__ idx_i,
                      const int* __restrict__ idx_j,
                      float* __restrict__ out_rij)       // d_out + 20000 (f32)
{
    __shared__ i4_ma act_all[2 * 32 * 16];   // 2 waves x (32 rows x 16 chunks)

    const int wave = threadIdx.x >> 6;
    const int lane = threadIdx.x & 63;
    i4_ma* act = act_all + wave * (32 * 16);

    const int pp = lane & 31;           // pair owned (both half-waves mirror)
    const int p0 = blockIdx.x * 64 + wave * 32;
    const int p = p0 + pp;
    const bool valid = (p < NP);

    // ---- phase 0: rij + radial basis, built DIRECTLY into B-frag registers ----
    int ai = 0, aj = 0;
    if (valid) { ai = idx_i[p]; aj = idx_j[p]; }
    float xi0 = g_Rf[3 * ai + 0], xi1 = g_Rf[3 * ai + 1], xi2 = g_Rf[3 * ai + 2];
    float xj0 = g_Rf[3 * aj + 0], xj1 = g_Rf[3 * aj + 1], xj2 = g_Rf[3 * aj + 2];
    float dx = xj0 - xi0, dy = xj1 - xi1, dz = xj2 - xi2;
    float rij = sqrtf(dx * dx + dy * dy + dz * dz + 1e-12f);
    if (lane < 32 && valid) out_rij[p] = rij;

    float fcut = 0.0f;
    if (valid && rij < 10.0f) {
        float xc = rij * 0.1f;
        float x3 = xc * xc * xc;
        fcut = 1.0f + x3 * (-10.0f + xc * (15.0f - 6.0f * xc));
    }
    const float mu0 = 4.5399929762484854e-05f;
    const float dmu = (1.0f - mu0) / 127.0f;
    const float wc = (2.0f / 128.0f) * (1.0f - mu0);
    const float NW2 = -(1.0f / (wc * wc)) * LOG2E;
    float er = FEXP2(-rij * LOG2E);

    const int q = lane >> 4;        // quad
    const int l15 = lane & 15;
    const int aseg = valid ? ai : -1;   // sentinel: invalid pairs never merge/fire

    // B-frag carry registers: bfrX[nt][kt] = x[pair nt*16+l15][k=kt*32+q*8 .. +7]
    bf16x8 bfrX[2][4];
    {
        float er_n[2], fc_n[2];
        er_n[0] = __shfl(er, l15, 64);      fc_n[0] = __shfl(fcut, l15, 64);
        er_n[1] = __shfl(er, 16 + l15, 64); fc_n[1] = __shfl(fcut, 16 + l15, 64);
#pragma unroll
        for (int nt = 0; nt < 2; ++nt)
#pragma unroll
            for (int kt = 0; kt < 4; ++kt) {
                uint_t d[4];
#pragma unroll
                for (int jj = 0; jj < 4; ++jj) {
                    int g = kt * 32 + q * 8 + jj * 2;
                    float m0 = mu0 + (float)(g + 0) * dmu;
                    float m1 = mu0 + (float)(g + 1) * dmu;
                    float e0 = er_n[nt] - m0, e1 = er_n[nt] - m1;
                    d[jj] = pkbf(fc_n[nt] * FEXP2(NW2 * e0 * e0),
                                 fc_n[nt] * FEXP2(NW2 * e1 * e1));
                }
                i4_ma pk;
                pk.x = (int)d[0]; pk.y = (int)d[1]; pk.z = (int)d[2]; pk.w = (int)d[3];
                bfrX[nt][kt] = as_bf16x8(pk);
            }
    }

    for (int blk = 0; blk < NBLK; ++blk) {
#pragma unroll
        for (int li = 0; li < 4; ++li) {
            const int L = blk * 4 + li;
            const uint8_t* blob = g_blob + (size_t)L * BLOB_BYTES;
            const ushort_t* bw = (const ushort_t*)blob;
            const float* bb = (const float*)(blob + BLOB_W_BYTES);

            // acc initialized to folded bias (b*log2e - 1)
            f32x4 acc[2][8];
#pragma unroll
            for (int mt = 0; mt < 8; ++mt) {
                const f32x4 bias = *(const f32x4*)(bb + mt * 16 + q * 4);
                acc[0][mt] = bias;
                acc[1][mt] = bias;
            }
#pragma unroll
            for (int kt = 0; kt < 4; ++kt) {
                const int cc = kt * 4 + q;
                bf16x8 b0, b1;
                if (li == 0) {
                    b0 = bfrX[0][kt];
                    b1 = bfrX[1][kt];
                } else {
                    b0 = as_bf16x8(act[(l15) * 16 + (cc ^ l15)]);
                    b1 = as_bf16x8(act[(16 + l15) * 16 + (cc ^ l15)]);
                    if (li == 2) { bfrX[0][kt] = b0; bfrX[1][kt] = b1; }  // carry x
                }
#pragma unroll
                for (int mt = 0; mt < 8; ++mt) {
                    bf16x8 afr = as_bf16x8(
                        *(const i4_ma*)(bw + (mt * 16 + l15) * 128 + 8 * (cc ^ l15)));
                    acc[0][mt] = __builtin_amdgcn_mfma_f32_16x16x32_bf16(
                        afr, b0, acc[0][mt], 0, 0, 0);
                    acc[1][mt] = __builtin_amdgcn_mfma_f32_16x16x32_bf16(
                        afr, b1, acc[1][mt], 0, 0, 0);
                }
            }

            if (li < 3) {
                // ssp + pack + in-place LDS write
#pragma unroll
                for (int mt = 0; mt < 8; ++mt) {
                    const int c = mt * 2 + (q >> 1);   // feature chunk
#pragma unroll
                    for (int nt = 0; nt < 2; ++nt) {
                        float u0 = ssp_u(acc[nt][mt][0]);
                        float u1 = ssp_u(acc[nt][mt][1]);
                        float u2 = ssp_u(acc[nt][mt][2]);
                        float u3 = ssp_u(acc[nt][mt][3]);
                        u2_ma pk;
                        pk.x = pkbf(u0, u1);
                        pk.y = pkbf(u2, u3);
                        const int rp = nt * 16 + l15;
                        ((u2_ma*)&act[rp * 16 + (c ^ l15)])[q & 1] = pk;
                    }
                }
            } else {
                // head: out_e = u3 @ (ln2*oWf) + oBf, then sorted-segment reduction
                const float* hw = g_oWfF + blk * 256;
                const float ob0 = g_oBfF[blk * 2 + 0];
                const float ob1 = g_oBfF[blk * 2 + 1];
                float hs[2][2];
#pragma unroll
                for (int nt = 0; nt < 2; ++nt) {
                    float h0 = 0.f, h1 = 0.f;
#pragma unroll
                    for (int mt = 0; mt < 8; ++mt) {
#pragma unroll
                        for (int rr = 0; rr < 4; ++rr) {
                            float u = ssp_u(acc[nt][mt][rr]);
                            const int f = mt * 16 + q * 4 + rr;
                            h0 = fmaf(u, hw[f * 2 + 0], h0);
                            h1 = fmaf(u, hw[f * 2 + 1], h1);
                        }
                    }
                    h0 += __shfl_xor(h0, 16, 64);
                    h0 += __shfl_xor(h0, 32, 64);
                    h1 += __shfl_xor(h1, 16, 64);
                    h1 += __shfl_xor(h1, 32, 64);
                    hs[nt][0] = h0; hs[nt][1] = h1;
                }
                float c0v = (pp < 16) ? hs[0][0] : hs[1][0];
                float c1v = (pp < 16) ? hs[0][1] : hs[1][1];
                c0v += ob0; c1v += ob1;
                // segmented inclusive scan over the 32 sorted pairs (runs contiguous)
#pragma unroll
                for (int d = 1; d < 32; d <<= 1) {
                    float t0 = __shfl_up(c0v, d, 64);
                    float t1 = __shfl_up(c1v, d, 64);
                    int   an = __shfl_up(aseg, d, 64);
                    if (pp >= d && an == aseg) { c0v += t0; c1v += t1; }
                }
                int ain = __shfl_down(aseg, 1, 64);
                bool tail = (pp == 31) || (ain != aseg);
                if (lane < 32 && valid && tail) {
                    atomicAdd(&g_outs[(blk * NA + aseg) * 2 + 0], c0v);
                    atomicAdd(&g_outs[(blk * NA + aseg) * 2 + 1], c1v);
                }
            }
        }
    }
}

// ---------------- finalize: scale/shift + nhloss reduction ----------------
__global__ void finalize_kernel(const int* __restrict__ Z,
                                float* __restrict__ out_atoms)   // d_out (f32)
{
    __shared__ float red[256];
    const int a = blockIdx.x * 256 + threadIdx.x;
    float s = 0.f;
    if (a < NA) {
        float v[NBLK][2];
        float t0 = 0.f, t1 = 0.f;
#pragma unroll
        for (int b = 0; b < NBLK; ++b) {
            v[b][0] = g_outs[(b * NA + a) * 2 + 0];
            v[b][1] = g_outs[(b * NA + a) * 2 + 1];
            t0 += v[b][0]; t1 += v[b][1];
        }
        const int z = Z[a];
        out_atoms[a * 2 + 0] = t0 * g_scF[z]      + g_shF[z];
        out_atoms[a * 2 + 1] = t1 * g_scF[95 + z] + g_shF[95 + z];
#pragma unroll
        for (int b = 1; b < NBLK; ++b)
#pragma unroll
            for (int o = 0; o < 2; ++o) {
                float x2 = v[b][o] * v[b][o];
                float p2 = v[b - 1][o] * v[b - 1][o];
                s += x2 / (x2 + p2 + 1e-7f);
            }
    }
    red[threadIdx.x] = s;
    __syncthreads();
    for (int st = 128; st > 0; st >>= 1) {
        if (threadIdx.x < st) red[threadIdx.x] += red[threadIdx.x + st];
        __syncthreads();
    }
    if (threadIdx.x == 0) atomicAdd(&g_nh[0], red[0]);
}

__global__ void nh_write(float* __restrict__ out_nh)
{
    out_nh[0] = g_nh[0] * (1.0f / 20000.0f);
}

// ---------------- launch ----------------
extern "C" void kernel_launch(void* const* d_in, const int* in_sizes, int n_in,
                              void* d_out, int out_size, void* d_ws, size_t ws_size,
                              hipStream_t stream)
{
    const int* Z     = (const int*)d_in[0];
    const void* R    = d_in[1];
    const int* idx_i = (const int*)d_in[2];
    const int* idx_j = (const int*)d_in[3];
    const void* iW   = d_in[4];
    const void* iB   = d_in[5];
    const void* oW   = d_in[6];
    const void* oB   = d_in[7];
    const void* oWf  = d_in[8];
    const void* oBf  = d_in[9];
    const void* scales = d_in[10];
    const void* shifts = d_in[11];

    float* out_f = (float*)d_out;   // [0,20000): outputs  [20000,270000): rij  [270000]: nhloss

    zero_outs<<<(NBLK * NA * 2 + 255) / 256, 256, 0, stream>>>();
    prep_weights<<<NL, 256, 0, stream>>>(iW, iB, oW, oB);
    prep_misc<<<(NA * 3 + 255) / 256, 256, 0, stream>>>(R, oWf, oBf, scales, shifts, iW);
    pairs_mlp_kernel<<<(NP + 63) / 64, 128, 0, stream>>>(idx_i, idx_j, out_f + 2 * NA);
    finalize_kernel<<<(NA + 255) / 256, 256, 0, stream>>>(Z, out_f);
    nh_write<<<1, 1, 0, stream>>>(out_f + 2 * NA + NP);
}

// Round 9
// 358.863 us; speedup vs baseline: 1.9917x; 1.9917x over previous
//
#include <hip/hip_runtime.h>
#include <stdint.h>

// ---------------- problem constants ----------------
#define NP   250000
#define NA   10000
#define NBLK 5
#define NL   20            // 5 blocks x (2 iW + 2 oW) layers
#define BLOB_W_BYTES 32768               // 128x128 bf16, row=out-feature, XOR-swizzled chunks
#define BLOB_BYTES   33280               // + 128 fp32 folded biases (512 B)

#define LOG2E 1.4426950408889634f
#define LN2   0.6931471805599453f

typedef __bf16 bf16x8 __attribute__((ext_vector_type(8)));
typedef float  f32x4  __attribute__((ext_vector_type(4)));
typedef unsigned short ushort_t;
typedef unsigned int   uint_t;
typedef int4  i4_ma __attribute__((may_alias));
typedef uint2 u2_ma __attribute__((may_alias));

// raw single-instruction transcendentals (v_exp_f32 / v_log_f32); args bounded
#if __has_builtin(__builtin_amdgcn_exp2f)
#define FEXP2(x) __builtin_amdgcn_exp2f(x)
#else
#define FEXP2(x) exp2f(x)
#endif
#if __has_builtin(__builtin_amdgcn_logf)
#define FLOG2(x) __builtin_amdgcn_logf(x)
#else
#define FLOG2(x) log2f(x)
#endif

// ---------------- static device scratch ----------------
__device__ uint8_t g_blob[NL * BLOB_BYTES];   // swizzled bf16 weights + folded f32 biases
__device__ float   g_outs[NBLK * NA * 2];     // per-block per-atom segment sums
__device__ float   g_nh[1];
__device__ float   g_Rf[NA * 3];
__device__ float   g_oWfF[NBLK * 128 * 2];    // ln2-prescaled head weights
__device__ float   g_oBfF[NBLK * 2];          // head biases (unmodified)
__device__ float   g_scF[190];
__device__ float   g_shF[190];

static __device__ __forceinline__ float bf2f(ushort_t u) {
    return __uint_as_float(((uint_t)u) << 16);
}
static __device__ __forceinline__ ushort_t f2bf(float f) {   // RNE (prep only)
    uint_t u = __float_as_uint(f);
    u += 0x7fffu + ((u >> 16) & 1u);
    return (ushort_t)(u >> 16);
}
static __device__ __forceinline__ bf16x8 as_bf16x8(i4_ma v) {
    union { i4_ma i; bf16x8 b; } u; u.i = v; return u.b;
}
// pack 2 floats -> bf16x2 dword by truncation (1 VALU op). RELATIVE error --
// safe because stored u decays with the signal (round-5 lesson).
static __device__ __forceinline__ uint_t pkbf(float a, float b) {
    return __byte_perm(__float_as_uint(a), __float_as_uint(b), 0x7632);
}
// stored activation: u = y/ln2 = log2(0.5 + 2^(t-1)); -1 folded into bias.
static __device__ __forceinline__ float ssp_u(float accv) {
    return FLOG2(0.5f + FEXP2(accv));
}

// dtype auto-detection (validated round 4: inputs are f32; keep as insurance)
static __device__ __forceinline__ bool detect_is_f32(const ushort_t* probe) {
    __shared__ int flag;
    if (threadIdx.x == 0) flag = 0;
    __syncthreads();
    if (threadIdx.x < 256) {
        float v = fabsf(bf2f(probe[2 * threadIdx.x]));
        if (!(v <= 64.0f)) flag = 1;
    }
    __syncthreads();
    return flag != 0;
}
static __device__ __forceinline__ float in_elt(const void* p, int i, bool isf32) {
    return isf32 ? ((const float*)p)[i] : bf2f(((const ushort_t*)p)[i]);
}

// ---------------- zero accumulators ----------------
__global__ void zero_outs()
{
    const int t = blockIdx.x * 256 + threadIdx.x;
    if (t < NBLK * NA * 2) g_outs[t] = 0.0f;
    if (t == 0) g_nh[0] = 0.0f;
}

// ---------------- weight prep ----------------
// blob[L]: row m (out-feature) * 128 bf16; chunk c=k>>3 at 8*((k>>3)^(m&15))+(k&7).
// L==0: W prescaled by log2e (input is raw basis). L>=1: W unscaled (input is u).
// bias = b*log2e - 1 (implements the s->u shift inside the acc).
__global__ void prep_weights(const void* __restrict__ iW, const void* __restrict__ iB,
                             const void* __restrict__ oW, const void* __restrict__ oB)
{
    const bool isf32 = detect_is_f32((const ushort_t*)iW);
    const int L = blockIdx.x;           // 0..19
    const int b = L >> 2, li = L & 3;
    const void* srcW = (li < 2) ? iW : oW;
    const void* srcB = (li < 2) ? iB : oB;
    const int lyr = (li < 2) ? (b * 2 + li) : (b * 2 + li - 2);
    const int wofs = lyr * 16384;
    const int bofs = lyr * 128;
    uint8_t* blob = g_blob + (size_t)L * BLOB_BYTES;
    ushort_t* dw = (ushort_t*)blob;
    float*    db = (float*)(blob + BLOB_W_BYTES);
    for (int idx = threadIdx.x; idx < 16384; idx += blockDim.x) {
        int k = idx >> 7, n = idx & 127;               // src: W[k][n] (k=in, n=out)
        float w = in_elt(srcW, wofs + k * 128 + n, isf32);
        if (L == 0) w *= LOG2E;
        dw[n * 128 + 8 * ((k >> 3) ^ (n & 15)) + (k & 7)] = f2bf(w);
    }
    for (int m = threadIdx.x; m < 128; m += blockDim.x)
        db[m] = in_elt(srcB, bofs + m, isf32) * LOG2E - 1.0f;
}

// canonical f32 copies; head weights prescaled by ln2 (u -> y factor)
__global__ void prep_misc(const void* __restrict__ R, const void* __restrict__ oWf,
                          const void* __restrict__ oBf, const void* __restrict__ scales,
                          const void* __restrict__ shifts, const void* __restrict__ iW)
{
    const bool isf32 = detect_is_f32((const ushort_t*)iW);
    const int t = blockIdx.x * 256 + threadIdx.x;
    if (t < NA * 3)      g_Rf[t]   = in_elt(R, t, isf32);
    if (t < NBLK * 256)  g_oWfF[t] = LN2 * in_elt(oWf, t, isf32);
    if (t < NBLK * 2)    g_oBfF[t] = in_elt(oBf, t, isf32);
    if (t < 190)         g_scF[t]  = in_elt(scales, t, isf32);
    if (t < 190)         g_shF[t]  = in_elt(shifts, t, isf32);
}

// ---------------- fused per-pair MLP, wg-shared weights ----------------
// wg = 256 threads = 4 waves x 32 pairs. Per layer: barrier -> cooperative
// stage of the 32 KB weight blob into LDS (coalesced b128) -> barrier ->
// each wave computes from LDS A-frags + its private 8 KB in-place act region.
// x2 carried across li2/li3 in 32 VGPRs (safe: launch_bounds(256,2) -> 256-reg
// cap, ~140 needed -> no spill; round-8's spill came from the 128-reg cap).
// LDS = 32 KB weights + 4 x 8 KB act = 64 KB -> 2 wg/CU = 8 waves/CU.
__global__ __launch_bounds__(256, 2)
void pairs_mlp_kernel(const int* __restrict__ idx_i,
                      const int* __restrict__ idx_j,
                      float* __restrict__ out_rij)       // d_out + 20000 (f32)
{
    __shared__ i4_ma w_lds[2048];            // 32 KB: swizzled weight blob of layer L
    __shared__ i4_ma act_all[4 * 32 * 16];   // 4 waves x (32 rows x 16 chunks)

    const int wave = threadIdx.x >> 6;
    const int lane = threadIdx.x & 63;
    i4_ma* act = act_all + wave * (32 * 16);

    const int pp = lane & 31;           // pair owned (both half-waves mirror)
    const int p0 = blockIdx.x * 128 + wave * 32;
    const int p = p0 + pp;
    const bool valid = (p < NP);

    // ---- phase 0: rij + radial basis, built DIRECTLY into B-frag registers ----
    int ai = 0, aj = 0;
    if (valid) { ai = idx_i[p]; aj = idx_j[p]; }
    float xi0 = g_Rf[3 * ai + 0], xi1 = g_Rf[3 * ai + 1], xi2 = g_Rf[3 * ai + 2];
    float xj0 = g_Rf[3 * aj + 0], xj1 = g_Rf[3 * aj + 1], xj2 = g_Rf[3 * aj + 2];
    float dx = xj0 - xi0, dy = xj1 - xi1, dz = xj2 - xi2;
    float rij = sqrtf(dx * dx + dy * dy + dz * dz + 1e-12f);
    if (lane < 32 && valid) out_rij[p] = rij;

    float fcut = 0.0f;
    if (valid && rij < 10.0f) {
        float xc = rij * 0.1f;
        float x3 = xc * xc * xc;
        fcut = 1.0f + x3 * (-10.0f + xc * (15.0f - 6.0f * xc));
    }
    const float mu0 = 4.5399929762484854e-05f;
    const float dmu = (1.0f - mu0) / 127.0f;
    const float wc = (2.0f / 128.0f) * (1.0f - mu0);
    const float NW2 = -(1.0f / (wc * wc)) * LOG2E;
    float er = FEXP2(-rij * LOG2E);

    const int q = lane >> 4;        // quad
    const int l15 = lane & 15;
    const int aseg = valid ? ai : -1;   // sentinel: invalid pairs never merge/fire

    // B-frag carry registers: bfrX[nt][kt] = x[pair nt*16+l15][k=kt*32+q*8 .. +7]
    bf16x8 bfrX[2][4];
    {
        float er_n[2], fc_n[2];
        er_n[0] = __shfl(er, l15, 64);      fc_n[0] = __shfl(fcut, l15, 64);
        er_n[1] = __shfl(er, 16 + l15, 64); fc_n[1] = __shfl(fcut, 16 + l15, 64);
#pragma unroll
        for (int nt = 0; nt < 2; ++nt)
#pragma unroll
            for (int kt = 0; kt < 4; ++kt) {
                uint_t d[4];
#pragma unroll
                for (int jj = 0; jj < 4; ++jj) {
                    int g = kt * 32 + q * 8 + jj * 2;
                    float m0 = mu0 + (float)(g + 0) * dmu;
                    float m1 = mu0 + (float)(g + 1) * dmu;
                    float e0 = er_n[nt] - m0, e1 = er_n[nt] - m1;
                    d[jj] = pkbf(fc_n[nt] * FEXP2(NW2 * e0 * e0),
                                 fc_n[nt] * FEXP2(NW2 * e1 * e1));
                }
                i4_ma pk;
                pk.x = (int)d[0]; pk.y = (int)d[1]; pk.z = (int)d[2]; pk.w = (int)d[3];
                bfrX[nt][kt] = as_bf16x8(pk);
            }
    }

    for (int blk = 0; blk < NBLK; ++blk) {
#pragma unroll
        for (int li = 0; li < 4; ++li) {
            const int L = blk * 4 + li;
            const i4_ma* gW = (const i4_ma*)(g_blob + (size_t)L * BLOB_BYTES);
            const float* bb = (const float*)(g_blob + (size_t)L * BLOB_BYTES + BLOB_W_BYTES);

            // ---- cooperative weight staging (all 4 waves) ----
            __syncthreads();              // everyone done reading W_{L-1}
#pragma unroll
            for (int it = 0; it < 8; ++it)
                w_lds[threadIdx.x + it * 256] = gW[threadIdx.x + it * 256];
            __syncthreads();

            // acc initialized to folded bias (b*log2e - 1)
            f32x4 acc[2][8];
#pragma unroll
            for (int mt = 0; mt < 8; ++mt) {
                const f32x4 bias = *(const f32x4*)(bb + mt * 16 + q * 4);
                acc[0][mt] = bias;
                acc[1][mt] = bias;
            }
#pragma unroll
            for (int kt = 0; kt < 4; ++kt) {
                const int cc = kt * 4 + q;
                bf16x8 b0, b1;
                if (li == 0) {
                    b0 = bfrX[0][kt];
                    b1 = bfrX[1][kt];
                } else {
                    b0 = as_bf16x8(act[(l15) * 16 + (cc ^ l15)]);
                    b1 = as_bf16x8(act[(16 + l15) * 16 + (cc ^ l15)]);
                    if (li == 2) { bfrX[0][kt] = b0; bfrX[1][kt] = b1; }  // carry x
                }
#pragma unroll
                for (int mt = 0; mt < 8; ++mt) {
                    bf16x8 afr = as_bf16x8(w_lds[(mt * 16 + l15) * 16 + (cc ^ l15)]);
                    acc[0][mt] = __builtin_amdgcn_mfma_f32_16x16x32_bf16(
                        afr, b0, acc[0][mt], 0, 0, 0);
                    acc[1][mt] = __builtin_amdgcn_mfma_f32_16x16x32_bf16(
                        afr, b1, acc[1][mt], 0, 0, 0);
                }
            }

            if (li < 3) {
                // ssp + pack + in-place LDS write (wave-private region; all this
                // layer's ds_reads precede these writes in wave program order)
#pragma unroll
                for (int mt = 0; mt < 8; ++mt) {
                    const int c = mt * 2 + (q >> 1);   // feature chunk
#pragma unroll
                    for (int nt = 0; nt < 2; ++nt) {
                        float u0 = ssp_u(acc[nt][mt][0]);
                        float u1 = ssp_u(acc[nt][mt][1]);
                        float u2 = ssp_u(acc[nt][mt][2]);
                        float u3 = ssp_u(acc[nt][mt][3]);
                        u2_ma pk;
                        pk.x = pkbf(u0, u1);
                        pk.y = pkbf(u2, u3);
                        const int rp = nt * 16 + l15;
                        ((u2_ma*)&act[rp * 16 + (c ^ l15)])[q & 1] = pk;
                    }
                }
            } else {
                // head: out_e = u3 @ (ln2*oWf) + oBf, then sorted-segment reduction
                const float* hw = g_oWfF + blk * 256;
                const float ob0 = g_oBfF[blk * 2 + 0];
                const float ob1 = g_oBfF[blk * 2 + 1];
                float hs[2][2];
#pragma unroll
                for (int nt = 0; nt < 2; ++nt) {
                    float h0 = 0.f, h1 = 0.f;
#pragma unroll
                    for (int mt = 0; mt < 8; ++mt) {
#pragma unroll
                        for (int rr = 0; rr < 4; ++rr) {
                            float u = ssp_u(acc[nt][mt][rr]);
                            const int f = mt * 16 + q * 4 + rr;
                            h0 = fmaf(u, hw[f * 2 + 0], h0);
                            h1 = fmaf(u, hw[f * 2 + 1], h1);
                        }
                    }
                    h0 += __shfl_xor(h0, 16, 64);
                    h0 += __shfl_xor(h0, 32, 64);
                    h1 += __shfl_xor(h1, 16, 64);
                    h1 += __shfl_xor(h1, 32, 64);
                    hs[nt][0] = h0; hs[nt][1] = h1;
                }
                float c0v = (pp < 16) ? hs[0][0] : hs[1][0];
                float c1v = (pp < 16) ? hs[0][1] : hs[1][1];
                c0v += ob0; c1v += ob1;
                // segmented inclusive scan over the 32 sorted pairs (runs contiguous)
#pragma unroll
                for (int d = 1; d < 32; d <<= 1) {
                    float t0 = __shfl_up(c0v, d, 64);
                    float t1 = __shfl_up(c1v, d, 64);
                    int   an = __shfl_up(aseg, d, 64);
                    if (pp >= d && an == aseg) { c0v += t0; c1v += t1; }
                }
                int ain = __shfl_down(aseg, 1, 64);
                bool tail = (pp == 31) || (ain != aseg);
                if (lane < 32 && valid && tail) {
                    atomicAdd(&g_outs[(blk * NA + aseg) * 2 + 0], c0v);
                    atomicAdd(&g_outs[(blk * NA + aseg) * 2 + 1], c1v);
                }
            }
        }
    }
}

// ---------------- finalize: scale/shift + nhloss reduction ----------------
__global__ void finalize_kernel(const int* __restrict__ Z,
                                float* __restrict__ out_atoms)   // d_out (f32)
{
    __shared__ float red[256];
    const int a = blockIdx.x * 256 + threadIdx.x;
    float s = 0.f;
    if (a < NA) {
        float v[NBLK][2];
        float t0 = 0.f, t1 = 0.f;
#pragma unroll
        for (int b = 0; b < NBLK; ++b) {
            v[b][0] = g_outs[(b * NA + a) * 2 + 0];
            v[b][1] = g_outs[(b * NA + a) * 2 + 1];
            t0 += v[b][0]; t1 += v[b][1];
        }
        const int z = Z[a];
        out_atoms[a * 2 + 0] = t0 * g_scF[z]      + g_shF[z];
        out_atoms[a * 2 + 1] = t1 * g_scF[95 + z] + g_shF[95 + z];
#pragma unroll
        for (int b = 1; b < NBLK; ++b)
#pragma unroll
            for (int o = 0; o < 2; ++o) {
                float x2 = v[b][o] * v[b][o];
                float p2 = v[b - 1][o] * v[b - 1][o];
                s += x2 / (x2 + p2 + 1e-7f);
            }
    }
    red[threadIdx.x] = s;
    __syncthreads();
    for (int st = 128; st > 0; st >>= 1) {
        if (threadIdx.x < st) red[threadIdx.x] += red[threadIdx.x + st];
        __syncthreads();
    }
    if (threadIdx.x == 0) atomicAdd(&g_nh[0], red[0]);
}

__global__ void nh_write(float* __restrict__ out_nh)
{
    out_nh[0] = g_nh[0] * (1.0f / 20000.0f);
}

// ---------------- launch ----------------
extern "C" void kernel_launch(void* const* d_in, const int* in_sizes, int n_in,
                              void* d_out, int out_size, void* d_ws, size_t ws_size,
                              hipStream_t stream)
{
    const int* Z     = (const int*)d_in[0];
    const void* R    = d_in[1];
    const int* idx_i = (const int*)d_in[2];
    const int* idx_j = (const int*)d_in[3];
    const void* iW   = d_in[4];
    const void* iB   = d_in[5];
    const void* oW   = d_in[6];
    const void* oB   = d_in[7];
    const void* oWf  = d_in[8];
    const void* oBf  = d_in[9];
    const void* scales = d_in[10];
    const void* shifts = d_in[11];

    float* out_f = (float*)d_out;   // [0,20000): outputs  [20000,270000): rij  [270000]: nhloss

    zero_outs<<<(NBLK * NA * 2 + 255) / 256, 256, 0, stream>>>();
    prep_weights<<<NL, 256, 0, stream>>>(iW, iB, oW, oB);
    prep_misc<<<(NA * 3 + 255) / 256, 256, 0, stream>>>(R, oWf, oBf, scales, shifts, iW);
    pairs_mlp_kernel<<<(NP + 127) / 128, 256, 0, stream>>>(idx_i, idx_j, out_f + 2 * NA);
    finalize_kernel<<<(NA + 255) / 256, 256, 0, stream>>>(Z, out_f);
    nh_write<<<1, 1, 0, stream>>>(out_f + 2 * NA + NP);
}

// Round 11
// 337.633 us; speedup vs baseline: 2.1170x; 1.0629x over previous
//
#include <hip/hip_runtime.h>
#include <stdint.h>

// ---------------- problem constants ----------------
#define NP   250000
#define NA   10000
#define NBLK 5
#define NL   20            // 5 blocks x (2 iW + 2 oW) layers
#define BLOB_W_BYTES 16384               // 128x128 fp8 e4m3, row=out-feature, XOR-swizzled
#define BLOB_BYTES   16896               // + 128 fp32 folded biases (512 B)

#define LOG2E 1.4426950408889634f
#define LN2   0.6931471805599453f

typedef float  f32x4  __attribute__((ext_vector_type(4)));
typedef unsigned short ushort_t;
typedef unsigned int   uint_t;
typedef int4  i4_ma __attribute__((may_alias));
typedef uint2 u2_ma __attribute__((may_alias));
typedef uint_t u1_ma __attribute__((may_alias));

// raw single-instruction transcendentals (v_exp_f32 / v_log_f32); args bounded
#if __has_builtin(__builtin_amdgcn_exp2f)
#define FEXP2(x) __builtin_amdgcn_exp2f(x)
#else
#define FEXP2(x) exp2f(x)
#endif
#if __has_builtin(__builtin_amdgcn_logf)
#define FLOG2(x) __builtin_amdgcn_logf(x)
#else
#define FLOG2(x) log2f(x)
#endif

// ---------------- static device scratch ----------------
__device__ uint8_t g_blob[NL * BLOB_BYTES];   // swizzled fp8 weights + folded f32 biases
__device__ float   g_outs[NBLK * NA * 2];     // per-block per-atom segment sums
__device__ float   g_nh[1];
__device__ float   g_Rf[NA * 3];
__device__ float   g_oWfF[NBLK * 128 * 2];    // ln2-prescaled head weights
__device__ float   g_oBfF[NBLK * 2];          // head biases (unmodified)
__device__ float   g_scF[190];
__device__ float   g_shF[190];

static __device__ __forceinline__ float bf2f(ushort_t u) {
    return __uint_as_float(((uint_t)u) << 16);
}
// e4m3fn (OCP) encoder, RNE — used in prep and as cvt fallback
static __device__ uint8_t f2fp8(float f) {
    uint_t u = __float_as_uint(f);
    uint8_t s = (uint8_t)((u >> 24) & 0x80);
    float af = fabsf(f);
    if (af != af) return (uint8_t)(s | 0x7F);
    if (af > 448.0f) return (uint8_t)(s | 0x7E);
    int e = (int)((u >> 23) & 0xFF) - 127;
    uint_t m = u & 0x7FFFFFu;
    if (e >= -6) {
        uint_t mant = m >> 20;
        uint_t rest = m & 0xFFFFFu;
        if (rest > 0x80000u || (rest == 0x80000u && (mant & 1u))) mant++;
        uint_t ee = (uint_t)(e + 7);
        if (mant == 8u) { mant = 0u; ee++; }
        if (ee > 15u || (ee == 15u && mant > 6u)) return (uint8_t)(s | 0x7E);
        return (uint8_t)(s | (ee << 3) | mant);
    }
    int qq = (int)rintf(af * 512.0f);      // subnormal: grid 2^-9
    if (qq > 7) return (uint8_t)(s | 0x08);
    return (uint8_t)(s | (uint_t)qq);
}
// hot-path pack: 2 f32 -> 2 fp8 bytes into low/high half of a dword.
// HI is a template param: the builtin's word-select operand must be an
// immediate (round-10 compile failure).
template <bool HI>
static __device__ __forceinline__ int cvtpk2(float a, float b, int old) {
#if __has_builtin(__builtin_amdgcn_cvt_pk_fp8_f32)
    return __builtin_amdgcn_cvt_pk_fp8_f32(a, b, old, HI);
#else
    int p = (int)f2fp8(a) | ((int)f2fp8(b) << 8);
    return HI ? (int)((old & 0x0000FFFF) | ((uint_t)p << 16))
              : (int)((old & 0xFFFF0000) | (uint_t)p);
#endif
}
static __device__ __forceinline__ long u2l(u2_ma v) {
    union { u2_ma u; long l; } x; x.u = v; return x.l;
}
// stored activation: u = y/ln2 = log2(0.5 + 2^(t-1)); -1 folded into bias.
static __device__ __forceinline__ float ssp_u(float accv) {
    return FLOG2(0.5f + FEXP2(accv));
}

// dtype auto-detection (validated round 4: inputs are f32; keep as insurance)
static __device__ __forceinline__ bool detect_is_f32(const ushort_t* probe) {
    __shared__ int flag;
    if (threadIdx.x == 0) flag = 0;
    __syncthreads();
    if (threadIdx.x < 256) {
        float v = fabsf(bf2f(probe[2 * threadIdx.x]));
        if (!(v <= 64.0f)) flag = 1;
    }
    __syncthreads();
    return flag != 0;
}
static __device__ __forceinline__ float in_elt(const void* p, int i, bool isf32) {
    return isf32 ? ((const float*)p)[i] : bf2f(((const ushort_t*)p)[i]);
}

// ---------------- zero accumulators ----------------
__global__ void zero_outs()
{
    const int t = blockIdx.x * 256 + threadIdx.x;
    if (t < NBLK * NA * 2) g_outs[t] = 0.0f;
    if (t == 0) g_nh[0] = 0.0f;
}

// ---------------- weight prep ----------------
// blob[L]: row m (out-feature) * 128 fp8 bytes; chunk c=k>>3 (8 B) at
// m*128 + 8*((k>>3)^(m&15)) + (k&7).
// L==0: W prescaled by log2e (input is raw basis). L>=1: W unscaled (input is u).
// bias = b*log2e - 1 (implements the s->u shift inside the acc).
__global__ void prep_weights(const void* __restrict__ iW, const void* __restrict__ iB,
                             const void* __restrict__ oW, const void* __restrict__ oB)
{
    const bool isf32 = detect_is_f32((const ushort_t*)iW);
    const int L = blockIdx.x;           // 0..19
    const int b = L >> 2, li = L & 3;
    const void* srcW = (li < 2) ? iW : oW;
    const void* srcB = (li < 2) ? iB : oB;
    const int lyr = (li < 2) ? (b * 2 + li) : (b * 2 + li - 2);
    const int wofs = lyr * 16384;
    const int bofs = lyr * 128;
    uint8_t* blob = g_blob + (size_t)L * BLOB_BYTES;
    uint8_t* dw = blob;
    float*   db = (float*)(blob + BLOB_W_BYTES);
    for (int idx = threadIdx.x; idx < 16384; idx += blockDim.x) {
        int k = idx >> 7, n = idx & 127;               // src: W[k][n] (k=in, n=out)
        float w = in_elt(srcW, wofs + k * 128 + n, isf32);
        if (L == 0) w *= LOG2E;
        dw[n * 128 + 8 * ((k >> 3) ^ (n & 15)) + (k & 7)] = f2fp8(w);
    }
    for (int m = threadIdx.x; m < 128; m += blockDim.x)
        db[m] = in_elt(srcB, bofs + m, isf32) * LOG2E - 1.0f;
}

// canonical f32 copies; head weights prescaled by ln2 (u -> y factor)
__global__ void prep_misc(const void* __restrict__ R, const void* __restrict__ oWf,
                          const void* __restrict__ oBf, const void* __restrict__ scales,
                          const void* __restrict__ shifts, const void* __restrict__ iW)
{
    const bool isf32 = detect_is_f32((const ushort_t*)iW);
    const int t = blockIdx.x * 256 + threadIdx.x;
    if (t < NA * 3)      g_Rf[t]   = in_elt(R, t, isf32);
    if (t < NBLK * 256)  g_oWfF[t] = LN2 * in_elt(oWf, t, isf32);
    if (t < NBLK * 2)    g_oBfF[t] = in_elt(oBf, t, isf32);
    if (t < 190)         g_scF[t]  = in_elt(scales, t, isf32);
    if (t < 190)         g_shF[t]  = in_elt(shifts, t, isf32);
}

// ---------------- fused per-pair MLP, fp8 path, wg-shared weights ----------------
// wg = 256 threads = 4 waves x 32 pairs. Per layer: barrier -> cooperative
// stage of the 16 KB fp8 weight blob into LDS -> barrier -> each wave computes
// from LDS A-frags + its private 4 KB in-place act region. x2 carried across
// li2/li3 in 16 VGPRs. LDS = 16 KB weights + 4 x 4 KB act = 32 KB ->
// 4 wg/CU (VGPR-capped at 128 via launch_bounds(256,4)) = 16 waves/CU.
__global__ __launch_bounds__(256, 4)
void pairs_mlp_kernel(const int* __restrict__ idx_i,
                      const int* __restrict__ idx_j,
                      float* __restrict__ out_rij)       // d_out + 20000 (f32)
{
    __shared__ i4_ma w_lds[1024];            // 16 KB: fp8 weight blob of layer L
    __shared__ u2_ma act_all[4 * 512];       // 4 waves x (32 rows x 16 chunks of 8B)

    const int wave = threadIdx.x >> 6;
    const int lane = threadIdx.x & 63;
    u2_ma* act = act_all + wave * 512;
    const u2_ma* wl2 = (const u2_ma*)w_lds;

    const int pp = lane & 31;           // pair owned (both half-waves mirror)
    const int p0 = blockIdx.x * 128 + wave * 32;
    const int p = p0 + pp;
    const bool valid = (p < NP);

    // ---- phase 0: rij + radial basis, built DIRECTLY into fp8 B-frag regs ----
    int ai = 0, aj = 0;
    if (valid) { ai = idx_i[p]; aj = idx_j[p]; }
    float xi0 = g_Rf[3 * ai + 0], xi1 = g_Rf[3 * ai + 1], xi2 = g_Rf[3 * ai + 2];
    float xj0 = g_Rf[3 * aj + 0], xj1 = g_Rf[3 * aj + 1], xj2 = g_Rf[3 * aj + 2];
    float dx = xj0 - xi0, dy = xj1 - xi1, dz = xj2 - xi2;
    float rij = sqrtf(dx * dx + dy * dy + dz * dz + 1e-12f);
    if (lane < 32 && valid) out_rij[p] = rij;

    float fcut = 0.0f;
    if (valid && rij < 10.0f) {
        float xc = rij * 0.1f;
        float x3 = xc * xc * xc;
        fcut = 1.0f + x3 * (-10.0f + xc * (15.0f - 6.0f * xc));
    }
    const float mu0 = 4.5399929762484854e-05f;
    const float dmu = (1.0f - mu0) / 127.0f;
    const float wc = (2.0f / 128.0f) * (1.0f - mu0);
    const float NW2 = -(1.0f / (wc * wc)) * LOG2E;
    float er = FEXP2(-rij * LOG2E);

    const int q = lane >> 4;        // quad
    const int l15 = lane & 15;
    const int aseg = valid ? ai : -1;   // sentinel: invalid pairs never merge/fire

    // B-frag carry regs: bfrX[nt][kt] = x[pair nt*16+l15][k=kt*32+q*8 .. +7] fp8
    u2_ma bfrX[2][4];
    {
        float er_n[2], fc_n[2];
        er_n[0] = __shfl(er, l15, 64);      fc_n[0] = __shfl(fcut, l15, 64);
        er_n[1] = __shfl(er, 16 + l15, 64); fc_n[1] = __shfl(fcut, 16 + l15, 64);
#pragma unroll
        for (int nt = 0; nt < 2; ++nt)
#pragma unroll
            for (int kt = 0; kt < 4; ++kt) {
                float v[8];
#pragma unroll
                for (int jj = 0; jj < 8; ++jj) {
                    int g = kt * 32 + q * 8 + jj;
                    float mu = mu0 + (float)g * dmu;
                    float e0 = er_n[nt] - mu;
                    v[jj] = fc_n[nt] * FEXP2(NW2 * e0 * e0);
                }
                int w0 = cvtpk2<false>(v[0], v[1], 0);
                w0 = cvtpk2<true>(v[2], v[3], w0);
                int w1 = cvtpk2<false>(v[4], v[5], 0);
                w1 = cvtpk2<true>(v[6], v[7], w1);
                bfrX[nt][kt].x = (uint_t)w0;
                bfrX[nt][kt].y = (uint_t)w1;
            }
    }

    for (int blk = 0; blk < NBLK; ++blk) {
#pragma unroll
        for (int li = 0; li < 4; ++li) {
            const int L = blk * 4 + li;
            const i4_ma* gW = (const i4_ma*)(g_blob + (size_t)L * BLOB_BYTES);
            const float* bb = (const float*)(g_blob + (size_t)L * BLOB_BYTES + BLOB_W_BYTES);

            // ---- cooperative weight staging (all 4 waves) ----
            __syncthreads();              // everyone done reading W_{L-1}
#pragma unroll
            for (int it = 0; it < 4; ++it)
                w_lds[threadIdx.x + it * 256] = gW[threadIdx.x + it * 256];
            __syncthreads();

            // acc initialized to folded bias (b*log2e - 1)
            f32x4 acc[2][8];
#pragma unroll
            for (int mt = 0; mt < 8; ++mt) {
                const f32x4 bias = *(const f32x4*)(bb + mt * 16 + q * 4);
                acc[0][mt] = bias;
                acc[1][mt] = bias;
            }
#pragma unroll
            for (int kt = 0; kt < 4; ++kt) {
                const int cc = kt * 4 + q;
                u2_ma b0, b1;
                if (li == 0) {
                    b0 = bfrX[0][kt];
                    b1 = bfrX[1][kt];
                } else {
                    b0 = act[(l15) * 16 + (cc ^ l15)];
                    b1 = act[(16 + l15) * 16 + (cc ^ l15)];
                    if (li == 2) { bfrX[0][kt] = b0; bfrX[1][kt] = b1; }  // carry x
                }
                const long lb0 = u2l(b0), lb1 = u2l(b1);
#pragma unroll
                for (int mt = 0; mt < 8; ++mt) {
                    const long la = u2l(wl2[(mt * 16 + l15) * 16 + (cc ^ l15)]);
                    acc[0][mt] = __builtin_amdgcn_mfma_f32_16x16x32_fp8_fp8(
                        la, lb0, acc[0][mt], 0, 0, 0);
                    acc[1][mt] = __builtin_amdgcn_mfma_f32_16x16x32_fp8_fp8(
                        la, lb1, acc[1][mt], 0, 0, 0);
                }
            }

            if (li < 3) {
                // ssp + fp8 pack + in-place LDS write (wave-private region; all
                // this layer's ds_reads precede these writes in program order)
#pragma unroll
                for (int mt = 0; mt < 8; ++mt) {
                    const int c = mt * 2 + (q >> 1);   // feature chunk (8 fp8)
#pragma unroll
                    for (int nt = 0; nt < 2; ++nt) {
                        float u0 = ssp_u(acc[nt][mt][0]);
                        float u1 = ssp_u(acc[nt][mt][1]);
                        float u2 = ssp_u(acc[nt][mt][2]);
                        float u3 = ssp_u(acc[nt][mt][3]);
                        int w = cvtpk2<false>(u0, u1, 0);
                        w = cvtpk2<true>(u2, u3, w);
                        const int rp = nt * 16 + l15;
                        ((u1_ma*)&act[rp * 16 + (c ^ (rp & 15))])[q & 1] = (uint_t)w;
                    }
                }
            } else {
                // head: out_e = u3 @ (ln2*oWf) + oBf, then sorted-segment reduction
                const float* hw = g_oWfF + blk * 256;
                const float ob0 = g_oBfF[blk * 2 + 0];
                const float ob1 = g_oBfF[blk * 2 + 1];
                float hs[2][2];
#pragma unroll
                for (int nt = 0; nt < 2; ++nt) {
                    float h0 = 0.f, h1 = 0.f;
#pragma unroll
                    for (int mt = 0; mt < 8; ++mt) {
#pragma unroll
                        for (int rr = 0; rr < 4; ++rr) {
                            float u = ssp_u(acc[nt][mt][rr]);
                            const int f = mt * 16 + q * 4 + rr;
                            h0 = fmaf(u, hw[f * 2 + 0], h0);
                            h1 = fmaf(u, hw[f * 2 + 1], h1);
                        }
                    }
                    h0 += __shfl_xor(h0, 16, 64);
                    h0 += __shfl_xor(h0, 32, 64);
                    h1 += __shfl_xor(h1, 16, 64);
                    h1 += __shfl_xor(h1, 32, 64);
                    hs[nt][0] = h0; hs[nt][1] = h1;
                }
                float c0v = (pp < 16) ? hs[0][0] : hs[1][0];
                float c1v = (pp < 16) ? hs[0][1] : hs[1][1];
                c0v += ob0; c1v += ob1;
                // segmented inclusive scan over the 32 sorted pairs (runs contiguous)
#pragma unroll
                for (int d = 1; d < 32; d <<= 1) {
                    float t0 = __shfl_up(c0v, d, 64);
                    float t1 = __shfl_up(c1v, d, 64);
                    int   an = __shfl_up(aseg, d, 64);
                    if (pp >= d && an == aseg) { c0v += t0; c1v += t1; }
                }
                int ain = __shfl_down(aseg, 1, 64);
                bool tail = (pp == 31) || (ain != aseg);
                if (lane < 32 && valid && tail) {
                    atomicAdd(&g_outs[(blk * NA + aseg) * 2 + 0], c0v);
                    atomicAdd(&g_outs[(blk * NA + aseg) * 2 + 1], c1v);
                }
            }
        }
    }
}

// ---------------- finalize: scale/shift + nhloss reduction ----------------
__global__ void finalize_kernel(const int* __restrict__ Z,
                                float* __restrict__ out_atoms)   // d_out (f32)
{
    __shared__ float red[256];
    const int a = blockIdx.x * 256 + threadIdx.x;
    float s = 0.f;
    if (a < NA) {
        float v[NBLK][2];
        float t0 = 0.f, t1 = 0.f;
#pragma unroll
        for (int b = 0; b < NBLK; ++b) {
            v[b][0] = g_outs[(b * NA + a) * 2 + 0];
            v[b][1] = g_outs[(b * NA + a) * 2 + 1];
            t0 += v[b][0]; t1 += v[b][1];
        }
        const int z = Z[a];
        out_atoms[a * 2 + 0] = t0 * g_scF[z]      + g_shF[z];
        out_atoms[a * 2 + 1] = t1 * g_scF[95 + z] + g_shF[95 + z];
#pragma unroll
        for (int b = 1; b < NBLK; ++b)
#pragma unroll
            for (int o = 0; o < 2; ++o) {
                float x2 = v[b][o] * v[b][o];
                float p2 = v[b - 1][o] * v[b - 1][o];
                s += x2 / (x2 + p2 + 1e-7f);
            }
    }
    red[threadIdx.x] = s;
    __syncthreads();
    for (int st = 128; st > 0; st >>= 1) {
        if (threadIdx.x < st) red[threadIdx.x] += red[threadIdx.x + st];
        __syncthreads();
    }
    if (threadIdx.x == 0) atomicAdd(&g_nh[0], red[0]);
}

__global__ void nh_write(float* __restrict__ out_nh)
{
    out_nh[0] = g_nh[0] * (1.0f / 20000.0f);
}

// ---------------- launch ----------------
extern "C" void kernel_launch(void* const* d_in, const int* in_sizes, int n_in,
                              void* d_out, int out_size, void* d_ws, size_t ws_size,
                              hipStream_t stream)
{
    const int* Z     = (const int*)d_in[0];
    const void* R    = d_in[1];
    const int* idx_i = (const int*)d_in[2];
    const int* idx_j = (const int*)d_in[3];
    const void* iW   = d_in[4];
    const void* iB   = d_in[5];
    const void* oW   = d_in[6];
    const void* oB   = d_in[7];
    const void* oWf  = d_in[8];
    const void* oBf  = d_in[9];
    const void* scales = d_in[10];
    const void* shifts = d_in[11];

    float* out_f = (float*)d_out;   // [0,20000): outputs  [20000,270000): rij  [270000]: nhloss

    zero_outs<<<(NBLK * NA * 2 + 255) / 256, 256, 0, stream>>>();
    prep_weights<<<NL, 256, 0, stream>>>(iW, iB, oW, oB);
    prep_misc<<<(NA * 3 + 255) / 256, 256, 0, stream>>>(R, oWf, oBf, scales, shifts, iW);
    pairs_mlp_kernel<<<(NP + 127) / 128, 256, 0, stream>>>(idx_i, idx_j, out_f + 2 * NA);
    finalize_kernel<<<(NA + 255) / 256, 256, 0, stream>>>(Z, out_f);
    nh_write<<<1, 1, 0, stream>>>(out_f + 2 * NA + NP);
}

// Round 12
// 279.622 us; speedup vs baseline: 2.5561x; 1.2075x over previous
//
#include <hip/hip_runtime.h>
#include <stdint.h>

// ---------------- problem constants ----------------
#define NP   250000
#define NA   10000
#define NBLK 5
#define NL   20            // 5 blocks x (2 iW + 2 oW) layers
#define BLOB_W_BYTES 16384               // 128x128 fp8 e4m3, row=out-feature, XOR-swizzled
#define BLOB_BYTES   16896               // + 128 fp32 folded biases (512 B)

#define LOG2E 1.4426950408889634f
#define LN2   0.6931471805599453f

typedef float  f32x4  __attribute__((ext_vector_type(4)));
typedef unsigned short ushort_t;
typedef unsigned int   uint_t;
typedef int4  i4_ma __attribute__((may_alias));
typedef uint2 u2_ma __attribute__((may_alias));
typedef uint_t u1_ma __attribute__((may_alias));

// raw single-instruction transcendentals (v_exp_f32 / v_log_f32); args bounded
#if __has_builtin(__builtin_amdgcn_exp2f)
#define FEXP2(x) __builtin_amdgcn_exp2f(x)
#else
#define FEXP2(x) exp2f(x)
#endif
#if __has_builtin(__builtin_amdgcn_logf)
#define FLOG2(x) __builtin_amdgcn_logf(x)
#else
#define FLOG2(x) log2f(x)
#endif

// ---------------- static device scratch ----------------
__device__ uint8_t g_blob[NL * BLOB_BYTES];   // swizzled fp8 weights + folded f32 biases
__device__ float   g_outs[NBLK * NA * 2];     // per-block per-atom segment sums
__device__ float   g_nh[1];
__device__ float   g_Rf[NA * 3];
__device__ float   g_oWfF[NBLK * 128 * 2];    // ln2-prescaled head weights
__device__ float   g_oBfF[NBLK * 2];          // head biases (unmodified)
__device__ float   g_scF[190];
__device__ float   g_shF[190];

static __device__ __forceinline__ float bf2f(ushort_t u) {
    return __uint_as_float(((uint_t)u) << 16);
}
// e4m3fn (OCP) encoder, RNE — used in prep and as cvt fallback
static __device__ uint8_t f2fp8(float f) {
    uint_t u = __float_as_uint(f);
    uint8_t s = (uint8_t)((u >> 24) & 0x80);
    float af = fabsf(f);
    if (af != af) return (uint8_t)(s | 0x7F);
    if (af > 448.0f) return (uint8_t)(s | 0x7E);
    int e = (int)((u >> 23) & 0xFF) - 127;
    uint_t m = u & 0x7FFFFFu;
    if (e >= -6) {
        uint_t mant = m >> 20;
        uint_t rest = m & 0xFFFFFu;
        if (rest > 0x80000u || (rest == 0x80000u && (mant & 1u))) mant++;
        uint_t ee = (uint_t)(e + 7);
        if (mant == 8u) { mant = 0u; ee++; }
        if (ee > 15u || (ee == 15u && mant > 6u)) return (uint8_t)(s | 0x7E);
        return (uint8_t)(s | (ee << 3) | mant);
    }
    int qq = (int)rintf(af * 512.0f);      // subnormal: grid 2^-9
    if (qq > 7) return (uint8_t)(s | 0x08);
    return (uint8_t)(s | (uint_t)qq);
}
// hot-path pack: 2 f32 -> 2 fp8 bytes into low/high half of a dword.
// HI is a template param (the builtin's word-select must be an immediate).
template <bool HI>
static __device__ __forceinline__ int cvtpk2(float a, float b, int old) {
#if __has_builtin(__builtin_amdgcn_cvt_pk_fp8_f32)
    return __builtin_amdgcn_cvt_pk_fp8_f32(a, b, old, HI);
#else
    int p = (int)f2fp8(a) | ((int)f2fp8(b) << 8);
    return HI ? (int)((old & 0x0000FFFF) | ((uint_t)p << 16))
              : (int)((old & 0xFFFF0000) | (uint_t)p);
#endif
}
static __device__ __forceinline__ long u2l(u2_ma v) {
    union { u2_ma u; long l; } x; x.u = v; return x.l;
}
// stored activation: u = y/ln2 = log2(0.5 + 2^(t-1)); -1 folded into bias.
static __device__ __forceinline__ float ssp_u(float accv) {
    return FLOG2(0.5f + FEXP2(accv));
}

// dtype auto-detection (validated round 4: inputs are f32; keep as insurance)
static __device__ __forceinline__ bool detect_is_f32(const ushort_t* probe) {
    __shared__ int flag;
    if (threadIdx.x == 0) flag = 0;
    __syncthreads();
    if (threadIdx.x < 256) {
        float v = fabsf(bf2f(probe[2 * threadIdx.x]));
        if (!(v <= 64.0f)) flag = 1;
    }
    __syncthreads();
    return flag != 0;
}
static __device__ __forceinline__ float in_elt(const void* p, int i, bool isf32) {
    return isf32 ? ((const float*)p)[i] : bf2f(((const ushort_t*)p)[i]);
}

// ---------------- weight prep (80 wg: layer L = bid>>2, quarter = bid&3) ----------------
// blob[L]: row m (out-feature) * 128 fp8 bytes; chunk c=k>>3 (8 B) at
// m*128 + 8*((k>>3)^(m&15)) + (k&7).
// L==0: W prescaled by log2e (input is raw basis). L>=1: W unscaled (input is u).
// bias = b*log2e - 1 (implements the s->u shift inside the acc).
__global__ void prep_weights(const void* __restrict__ iW, const void* __restrict__ iB,
                             const void* __restrict__ oW, const void* __restrict__ oB)
{
    const bool isf32 = detect_is_f32((const ushort_t*)iW);
    const int L = blockIdx.x >> 2;      // 0..19
    const int qr = blockIdx.x & 3;      // k-quarter
    const int b = L >> 2, li = L & 3;
    const void* srcW = (li < 2) ? iW : oW;
    const void* srcB = (li < 2) ? iB : oB;
    const int lyr = (li < 2) ? (b * 2 + li) : (b * 2 + li - 2);
    const int wofs = lyr * 16384;
    const int bofs = lyr * 128;
    uint8_t* blob = g_blob + (size_t)L * BLOB_BYTES;
    uint8_t* dw = blob;
    float*   db = (float*)(blob + BLOB_W_BYTES);
    for (int t = threadIdx.x; t < 4096; t += blockDim.x) {
        int idx = qr * 4096 + t;
        int k = idx >> 7, n = idx & 127;               // src: W[k][n] (k=in, n=out)
        float w = in_elt(srcW, wofs + k * 128 + n, isf32);
        if (L == 0) w *= LOG2E;
        dw[n * 128 + 8 * ((k >> 3) ^ (n & 15)) + (k & 7)] = f2fp8(w);
    }
    if (qr == 0)
        for (int m = threadIdx.x; m < 128; m += blockDim.x)
            db[m] = in_elt(srcB, bofs + m, isf32) * LOG2E - 1.0f;
}

// canonical f32 copies + accumulator zeroing (merged zero_outs)
__global__ void prep_misc(const void* __restrict__ R, const void* __restrict__ oWf,
                          const void* __restrict__ oBf, const void* __restrict__ scales,
                          const void* __restrict__ shifts, const void* __restrict__ iW)
{
    const bool isf32 = detect_is_f32((const ushort_t*)iW);
    const int t = blockIdx.x * 256 + threadIdx.x;
    if (t < NBLK * NA * 2) g_outs[t] = 0.0f;
    if (t == 0)          g_nh[0]  = 0.0f;
    if (t < NA * 3)      g_Rf[t]   = in_elt(R, t, isf32);
    if (t < NBLK * 256)  g_oWfF[t] = LN2 * in_elt(oWf, t, isf32);
    if (t < NBLK * 2)    g_oBfF[t] = in_elt(oBf, t, isf32);
    if (t < 190)         g_scF[t]  = in_elt(scales, t, isf32);
    if (t < 190)         g_shF[t]  = in_elt(shifts, t, isf32);
}

// ---------------- fused per-pair MLP, fp8 path, wg-shared weights ----------------
// wg = 256 threads = 4 waves x 32 pairs. Per layer: barrier -> cooperative
// stage of the 16 KB fp8 weight blob into LDS -> barrier -> each wave computes
// from LDS A-frags + its private 4 KB in-place act region. x2 carried across
// li2/li3 in 8 VGPRs (fp8). LDS = 16 KB weights + 4 x 4 KB act = 32 KB.
// launch_bounds(256,3): 170-reg unified cap -> acc(64 AGPR) + ~90 VGPR, NO
// spill (round-11's (256,4)=128-reg cap spilled 190 MB of scratch).
__global__ __launch_bounds__(256, 3)
void pairs_mlp_kernel(const int* __restrict__ idx_i,
                      const int* __restrict__ idx_j,
                      float* __restrict__ out_rij)       // d_out + 20000 (f32)
{
    __shared__ i4_ma w_lds[1024];            // 16 KB: fp8 weight blob of layer L
    __shared__ u2_ma act_all[4 * 512];       // 4 waves x (32 rows x 16 chunks of 8B)

    const int wave = threadIdx.x >> 6;
    const int lane = threadIdx.x & 63;
    u2_ma* act = act_all + wave * 512;
    const u2_ma* wl2 = (const u2_ma*)w_lds;

    const int pp = lane & 31;           // pair owned (both half-waves mirror)
    const int p0 = blockIdx.x * 128 + wave * 32;
    const int p = p0 + pp;
    const bool valid = (p < NP);

    // ---- phase 0: rij + radial basis, built DIRECTLY into fp8 B-frag regs ----
    int ai = 0, aj = 0;
    if (valid) { ai = idx_i[p]; aj = idx_j[p]; }
    float xi0 = g_Rf[3 * ai + 0], xi1 = g_Rf[3 * ai + 1], xi2 = g_Rf[3 * ai + 2];
    float xj0 = g_Rf[3 * aj + 0], xj1 = g_Rf[3 * aj + 1], xj2 = g_Rf[3 * aj + 2];
    float dx = xj0 - xi0, dy = xj1 - xi1, dz = xj2 - xi2;
    float rij = sqrtf(dx * dx + dy * dy + dz * dz + 1e-12f);
    if (lane < 32 && valid) out_rij[p] = rij;

    float fcut = 0.0f;
    if (valid && rij < 10.0f) {
        float xc = rij * 0.1f;
        float x3 = xc * xc * xc;
        fcut = 1.0f + x3 * (-10.0f + xc * (15.0f - 6.0f * xc));
    }
    const float mu0 = 4.5399929762484854e-05f;
    const float dmu = (1.0f - mu0) / 127.0f;
    const float wc = (2.0f / 128.0f) * (1.0f - mu0);
    const float NW2 = -(1.0f / (wc * wc)) * LOG2E;
    float er = FEXP2(-rij * LOG2E);

    const int q = lane >> 4;        // quad
    const int l15 = lane & 15;
    const int aseg = valid ? ai : -1;   // sentinel: invalid pairs never merge/fire

    // B-frag carry regs: bfrX[nt][kt] = x[pair nt*16+l15][k=kt*32+q*8 .. +7] fp8
    u2_ma bfrX[2][4];
    {
        float er_n[2], fc_n[2];
        er_n[0] = __shfl(er, l15, 64);      fc_n[0] = __shfl(fcut, l15, 64);
        er_n[1] = __shfl(er, 16 + l15, 64); fc_n[1] = __shfl(fcut, 16 + l15, 64);
#pragma unroll
        for (int nt = 0; nt < 2; ++nt)
#pragma unroll
            for (int kt = 0; kt < 4; ++kt) {
                float v[8];
#pragma unroll
                for (int jj = 0; jj < 8; ++jj) {
                    int g = kt * 32 + q * 8 + jj;
                    float mu = mu0 + (float)g * dmu;
                    float e0 = er_n[nt] - mu;
                    v[jj] = fc_n[nt] * FEXP2(NW2 * e0 * e0);
                }
                int w0 = cvtpk2<false>(v[0], v[1], 0);
                w0 = cvtpk2<true>(v[2], v[3], w0);
                int w1 = cvtpk2<false>(v[4], v[5], 0);
                w1 = cvtpk2<true>(v[6], v[7], w1);
                bfrX[nt][kt].x = (uint_t)w0;
                bfrX[nt][kt].y = (uint_t)w1;
            }
    }

    for (int blk = 0; blk < NBLK; ++blk) {
#pragma unroll
        for (int li = 0; li < 4; ++li) {
            const int L = blk * 4 + li;
            const i4_ma* gW = (const i4_ma*)(g_blob + (size_t)L * BLOB_BYTES);
            const float* bb = (const float*)(g_blob + (size_t)L * BLOB_BYTES + BLOB_W_BYTES);

            // ---- cooperative weight staging (all 4 waves) ----
            __syncthreads();              // everyone done reading W_{L-1}
#pragma unroll
            for (int it = 0; it < 4; ++it)
                w_lds[threadIdx.x + it * 256] = gW[threadIdx.x + it * 256];
            __syncthreads();

            // acc initialized to folded bias (b*log2e - 1)
            f32x4 acc[2][8];
#pragma unroll
            for (int mt = 0; mt < 8; ++mt) {
                const f32x4 bias = *(const f32x4*)(bb + mt * 16 + q * 4);
                acc[0][mt] = bias;
                acc[1][mt] = bias;
            }
#pragma unroll
            for (int kt = 0; kt < 4; ++kt) {
                const int cc = kt * 4 + q;
                u2_ma b0, b1;
                if (li == 0) {
                    b0 = bfrX[0][kt];
                    b1 = bfrX[1][kt];
                } else {
                    b0 = act[(l15) * 16 + (cc ^ l15)];
                    b1 = act[(16 + l15) * 16 + (cc ^ l15)];
                    if (li == 2) { bfrX[0][kt] = b0; bfrX[1][kt] = b1; }  // carry x
                }
                const long lb0 = u2l(b0), lb1 = u2l(b1);
#pragma unroll
                for (int mt = 0; mt < 8; ++mt) {
                    const long la = u2l(wl2[(mt * 16 + l15) * 16 + (cc ^ l15)]);
                    acc[0][mt] = __builtin_amdgcn_mfma_f32_16x16x32_fp8_fp8(
                        la, lb0, acc[0][mt], 0, 0, 0);
                    acc[1][mt] = __builtin_amdgcn_mfma_f32_16x16x32_fp8_fp8(
                        la, lb1, acc[1][mt], 0, 0, 0);
                }
            }

            if (li < 3) {
                // ssp + fp8 pack + in-place LDS write (wave-private region; all
                // this layer's ds_reads precede these writes in program order)
#pragma unroll
                for (int mt = 0; mt < 8; ++mt) {
                    const int c = mt * 2 + (q >> 1);   // feature chunk (8 fp8)
#pragma unroll
                    for (int nt = 0; nt < 2; ++nt) {
                        float u0 = ssp_u(acc[nt][mt][0]);
                        float u1 = ssp_u(acc[nt][mt][1]);
                        float u2 = ssp_u(acc[nt][mt][2]);
                        float u3 = ssp_u(acc[nt][mt][3]);
                        int w = cvtpk2<false>(u0, u1, 0);
                        w = cvtpk2<true>(u2, u3, w);
                        const int rp = nt * 16 + l15;
                        ((u1_ma*)&act[rp * 16 + (c ^ (rp & 15))])[q & 1] = (uint_t)w;
                    }
                }
            } else {
                // head: out_e = u3 @ (ln2*oWf) + oBf, then sorted-segment reduction
                const float* hw = g_oWfF + blk * 256;
                const float ob0 = g_oBfF[blk * 2 + 0];
                const float ob1 = g_oBfF[blk * 2 + 1];
                float hs[2][2];
#pragma unroll
                for (int nt = 0; nt < 2; ++nt) {
                    float h0 = 0.f, h1 = 0.f;
#pragma unroll
                    for (int mt = 0; mt < 8; ++mt) {
#pragma unroll
                        for (int rr = 0; rr < 4; ++rr) {
                            float u = ssp_u(acc[nt][mt][rr]);
                            const int f = mt * 16 + q * 4 + rr;
                            h0 = fmaf(u, hw[f * 2 + 0], h0);
                            h1 = fmaf(u, hw[f * 2 + 1], h1);
                        }
                    }
                    h0 += __shfl_xor(h0, 16, 64);
                    h0 += __shfl_xor(h0, 32, 64);
                    h1 += __shfl_xor(h1, 16, 64);
                    h1 += __shfl_xor(h1, 32, 64);
                    hs[nt][0] = h0; hs[nt][1] = h1;
                }
                float c0v = (pp < 16) ? hs[0][0] : hs[1][0];
                float c1v = (pp < 16) ? hs[0][1] : hs[1][1];
                c0v += ob0; c1v += ob1;
                // segmented inclusive scan over the 32 sorted pairs (runs contiguous)
#pragma unroll
                for (int d = 1; d < 32; d <<= 1) {
                    float t0 = __shfl_up(c0v, d, 64);
                    float t1 = __shfl_up(c1v, d, 64);
                    int   an = __shfl_up(aseg, d, 64);
                    if (pp >= d && an == aseg) { c0v += t0; c1v += t1; }
                }
                int ain = __shfl_down(aseg, 1, 64);
                bool tail = (pp == 31) || (ain != aseg);
                if (lane < 32 && valid && tail) {
                    atomicAdd(&g_outs[(blk * NA + aseg) * 2 + 0], c0v);
                    atomicAdd(&g_outs[(blk * NA + aseg) * 2 + 1], c1v);
                }
            }
        }
    }
}

// ---------------- finalize: scale/shift + nhloss reduction ----------------
__global__ void finalize_kernel(const int* __restrict__ Z,
                                float* __restrict__ out_atoms)   // d_out (f32)
{
    __shared__ float red[256];
    const int a = blockIdx.x * 256 + threadIdx.x;
    float s = 0.f;
    if (a < NA) {
        float v[NBLK][2];
        float t0 = 0.f, t1 = 0.f;
#pragma unroll
        for (int b = 0; b < NBLK; ++b) {
            v[b][0] = g_outs[(b * NA + a) * 2 + 0];
            v[b][1] = g_outs[(b * NA + a) * 2 + 1];
            t0 += v[b][0]; t1 += v[b][1];
        }
        const int z = Z[a];
        out_atoms[a * 2 + 0] = t0 * g_scF[z]      + g_shF[z];
        out_atoms[a * 2 + 1] = t1 * g_scF[95 + z] + g_shF[95 + z];
#pragma unroll
        for (int b = 1; b < NBLK; ++b)
#pragma unroll
            for (int o = 0; o < 2; ++o) {
                float x2 = v[b][o] * v[b][o];
                float p2 = v[b - 1][o] * v[b - 1][o];
                s += x2 / (x2 + p2 + 1e-7f);
            }
    }
    red[threadIdx.x] = s;
    __syncthreads();
    for (int st = 128; st > 0; st >>= 1) {
        if (threadIdx.x < st) red[threadIdx.x] += red[threadIdx.x + st];
        __syncthreads();
    }
    if (threadIdx.x == 0) atomicAdd(&g_nh[0], red[0]);
}

__global__ void nh_write(float* __restrict__ out_nh)
{
    out_nh[0] = g_nh[0] * (1.0f / 20000.0f);
}

// ---------------- launch ----------------
extern "C" void kernel_launch(void* const* d_in, const int* in_sizes, int n_in,
                              void* d_out, int out_size, void* d_ws, size_t ws_size,
                              hipStream_t stream)
{
    const int* Z     = (const int*)d_in[0];
    const void* R    = d_in[1];
    const int* idx_i = (const int*)d_in[2];
    const int* idx_j = (const int*)d_in[3];
    const void* iW   = d_in[4];
    const void* iB   = d_in[5];
    const void* oW   = d_in[6];
    const void* oB   = d_in[7];
    const void* oWf  = d_in[8];
    const void* oBf  = d_in[9];
    const void* scales = d_in[10];
    const void* shifts = d_in[11];

    float* out_f = (float*)d_out;   // [0,20000): outputs  [20000,270000): rij  [270000]: nhloss

    prep_weights<<<NL * 4, 256, 0, stream>>>(iW, iB, oW, oB);
    prep_misc<<<(NBLK * NA * 2 + 255) / 256, 256, 0, stream>>>(R, oWf, oBf, scales, shifts, iW);
    pairs_mlp_kernel<<<(NP + 127) / 128, 256, 0, stream>>>(idx_i, idx_j, out_f + 2 * NA);
    finalize_kernel<<<(NA + 255) / 256, 256, 0, stream>>>(Z, out_f);
    nh_write<<<1, 1, 0, stream>>>(out_f + 2 * NA + NP);
}